// Round 7
// baseline (38.819 us; speedup 1.0000x reference)
//
#include <hip/hip_runtime.h>
#include <math.h>

// Shapes (NCHW, f32):
//  x1: (8,128,128,128)  -> maxpool2 -> (8,128,64,64), tiled x2  in C
//  x2: (8, 32,256,256)  -> maxpool4 -> (8, 32,64,64), tiled x8  in C
//  x3: (8,  2,512,512)  -> maxpool8 -> (8,  2,64,64), tiled x128 in C
//  ff : (8,256,64,64)
//  out = relu(y1 + y2 + y3 + ff), (8,256,64,64)
//
// R6 = R5 with the y2 sizing bug fixed (y2 is 1,048,576 elems = 4 MB, not
// 2 MB; R5 only pooled batches 0-3 and read OOB for 4-7).
// Two-kernel streaming layout to fix DRAM access-pattern efficiency (R0 ran
// at ~3.4 TB/s effective = 54% of copy ceiling; scattered 256-B segments at
// 16-64 KB stride across 512 blocks = row-buffer thrash).
//  A) pool x2 -> y2 (4 MB ws), x3 -> y3 (256 KB ws); 16 KB contiguous reads.
//  B) block = (b, c1): reads the whole 64 KB x1 channel plane contiguously
//     (fused for out channels c1 and c1+128), 2x16 KB ff planes, writes
//     2x16 KB out planes; y2/y3 planes are tiny and L2/L3-hot.

__global__ __launch_bounds__(256) void pool_kernel(
    const float* __restrict__ x2, const float* __restrict__ x3,
    float* __restrict__ y2, float* __restrict__ y3)
{
    const int bid = blockIdx.x;
    if (bid < 4096) {
        // y2: 4x4 pool of x2. t -> [b][c2][h][w], one output per thread.
        const int t = bid * 256 + threadIdx.x;      // 0..1048575
        const int w = t & 63;
        const int h = (t >> 6) & 63;
        const int c = (t >> 12) & 31;
        const int b = t >> 17;                      // 0..7
        const float* p = x2 + (size_t)b * 2097152 + (size_t)c * 65536
                            + (size_t)(h * 4) * 256 + (size_t)w * 4;
        float m = -INFINITY;
        #pragma unroll
        for (int r = 0; r < 4; ++r) {
            const float4 a = *reinterpret_cast<const float4*>(p + (size_t)r * 256);
            m = fmaxf(m, fmaxf(fmaxf(a.x, a.y), fmaxf(a.z, a.w)));
        }
        y2[t] = m;
    } else {
        // y3: 8x8 pool of x3. t -> [b][c3][h][w], one output per thread.
        const int t = (bid - 4096) * 256 + threadIdx.x;  // 0..65535
        const int w = t & 63;
        const int h = (t >> 6) & 63;
        const int c = (t >> 12) & 1;
        const int b = t >> 13;                      // 0..7
        const float* p = x3 + (size_t)b * 524288 + (size_t)c * 262144
                            + (size_t)(h * 8) * 512 + (size_t)w * 8;
        float m = -INFINITY;
        #pragma unroll
        for (int r = 0; r < 8; ++r) {
            const float4 a  = *reinterpret_cast<const float4*>(p + (size_t)r * 512);
            const float4 c4 = *reinterpret_cast<const float4*>(p + (size_t)r * 512 + 4);
            m = fmaxf(m, fmaxf(fmaxf(fmaxf(a.x, a.y), fmaxf(a.z, a.w)),
                               fmaxf(fmaxf(c4.x, c4.y), fmaxf(c4.z, c4.w))));
        }
        y3[t] = m;
    }
}

__global__ __launch_bounds__(256) void combine_kernel(
    const float* __restrict__ x1, const float* __restrict__ ff,
    const float* __restrict__ y2, const float* __restrict__ y3,
    float* __restrict__ out)
{
    const int bid = blockIdx.x;     // 0..1023
    const int b   = bid >> 7;       // 0..7
    const int c   = bid & 127;      // x1 channel; serves out channels c, c+128

    const size_t x1_base = (size_t)b * 2097152 + (size_t)c * 16384;
    const size_t o0_base = (size_t)b * 1048576 + (size_t)c * 4096;
    const size_t o1_base = o0_base + (size_t)128 * 4096;
    const size_t y2_base = (size_t)b * 131072 + (size_t)(c & 31) * 4096;
    const size_t y3_base = (size_t)b * 8192   + (size_t)(c & 1)  * 4096;

    #pragma unroll
    for (int it = 0; it < 4; ++it) {
        const int f  = it * 256 + threadIdx.x;   // float4 index within plane
        const int w4 = f & 15;
        const int h  = f >> 4;

        const float* p = x1 + x1_base + (size_t)(2 * h) * 128 + (size_t)w4 * 8;
        const float4 a0 = *reinterpret_cast<const float4*>(p);
        const float4 a1 = *reinterpret_cast<const float4*>(p + 4);
        const float4 r0 = *reinterpret_cast<const float4*>(p + 128);
        const float4 r1 = *reinterpret_cast<const float4*>(p + 132);
        float4 y1v;
        y1v.x = fmaxf(fmaxf(a0.x, a0.y), fmaxf(r0.x, r0.y));
        y1v.y = fmaxf(fmaxf(a0.z, a0.w), fmaxf(r0.z, r0.w));
        y1v.z = fmaxf(fmaxf(a1.x, a1.y), fmaxf(r1.x, r1.y));
        y1v.w = fmaxf(fmaxf(a1.z, a1.w), fmaxf(r1.z, r1.w));

        const float4 y2v = *reinterpret_cast<const float4*>(y2 + y2_base + (size_t)f * 4);
        const float4 y3v = *reinterpret_cast<const float4*>(y3 + y3_base + (size_t)f * 4);
        const float4 f0  = *reinterpret_cast<const float4*>(ff + o0_base + (size_t)f * 4);
        const float4 f1  = *reinterpret_cast<const float4*>(ff + o1_base + (size_t)f * 4);

        float4 s;
        s.x = y1v.x + y2v.x + y3v.x;
        s.y = y1v.y + y2v.y + y3v.y;
        s.z = y1v.z + y2v.z + y3v.z;
        s.w = y1v.w + y2v.w + y3v.w;

        float4 u0, u1;
        u0.x = fmaxf(s.x + f0.x, 0.0f);
        u0.y = fmaxf(s.y + f0.y, 0.0f);
        u0.z = fmaxf(s.z + f0.z, 0.0f);
        u0.w = fmaxf(s.w + f0.w, 0.0f);
        u1.x = fmaxf(s.x + f1.x, 0.0f);
        u1.y = fmaxf(s.y + f1.y, 0.0f);
        u1.z = fmaxf(s.z + f1.z, 0.0f);
        u1.w = fmaxf(s.w + f1.w, 0.0f);

        *reinterpret_cast<float4*>(out + o0_base + (size_t)f * 4) = u0;
        *reinterpret_cast<float4*>(out + o1_base + (size_t)f * 4) = u1;
    }
}

// ---- Fallback (R0 structure) if ws_size is too small ----
__global__ __launch_bounds__(256) void fused_ff_block3(
    const float* __restrict__ x1, const float* __restrict__ x2,
    const float* __restrict__ x3, const float* __restrict__ ff,
    float* __restrict__ out)
{
    __shared__ float y2s[32][64];
    __shared__ float y3s[2][64];

    const int bid = blockIdx.x;
    const int b   = bid >> 6;
    const int h   = bid & 63;
    const int tid = threadIdx.x;

    if (tid < 128) {
        const int c3 = tid >> 6;
        const int w  = tid & 63;
        const float* p = x3 + (size_t)b * 524288 + (size_t)c3 * 262144
                            + (size_t)(h * 8) * 512 + (size_t)w * 8;
        float m = -INFINITY;
        #pragma unroll
        for (int r = 0; r < 8; ++r) {
            const float4 a = *reinterpret_cast<const float4*>(p + (size_t)r * 512);
            const float4 c = *reinterpret_cast<const float4*>(p + (size_t)r * 512 + 4);
            m = fmaxf(m, fmaxf(fmaxf(fmaxf(a.x, a.y), fmaxf(a.z, a.w)),
                               fmaxf(fmaxf(c.x, c.y), fmaxf(c.z, c.w))));
        }
        y3s[c3][w] = m;
    }
    #pragma unroll
    for (int v = tid; v < 2048; v += 256) {
        const int c2 = v >> 6;
        const int w  = v & 63;
        const float* p = x2 + (size_t)b * 2097152 + (size_t)c2 * 65536
                            + (size_t)(h * 4) * 256 + (size_t)w * 4;
        float m = -INFINITY;
        #pragma unroll
        for (int r = 0; r < 4; ++r) {
            const float4 a = *reinterpret_cast<const float4*>(p + (size_t)r * 256);
            m = fmaxf(m, fmaxf(fmaxf(a.x, a.y), fmaxf(a.z, a.w)));
        }
        y2s[c2][w] = m;
    }
    __syncthreads();
    const int w     = tid & 63;
    const int clane = tid >> 6;
    #pragma unroll 4
    for (int it = 0; it < 32; ++it) {
        const int c1 = it * 4 + clane;
        const float* p = x1 + (size_t)b * 2097152 + (size_t)c1 * 16384
                            + (size_t)(h * 2) * 128 + (size_t)w * 2;
        const float2 a  = *reinterpret_cast<const float2*>(p);
        const float2 bb = *reinterpret_cast<const float2*>(p + 128);
        const float p1 = fmaxf(fmaxf(a.x, a.y), fmaxf(bb.x, bb.y));
        const float s  = p1 + y2s[c1 & 31][w] + y3s[c1 & 1][w];
        const size_t obase = (size_t)b * 1048576 + (size_t)h * 64 + (size_t)w;
        const size_t o0 = obase + (size_t)c1 * 4096;
        const size_t o1 = obase + (size_t)(c1 + 128) * 4096;
        out[o0] = fmaxf(s + ff[o0], 0.0f);
        out[o1] = fmaxf(s + ff[o1], 0.0f);
    }
}

extern "C" void kernel_launch(void* const* d_in, const int* in_sizes, int n_in,
                              void* d_out, int out_size, void* d_ws, size_t ws_size,
                              hipStream_t stream) {
    const float* x1 = (const float*)d_in[0];
    const float* x2 = (const float*)d_in[1];
    const float* x3 = (const float*)d_in[2];
    const float* ff = (const float*)d_in[3];
    float* out = (float*)d_out;

    const size_t need = (size_t)(1048576 + 65536) * sizeof(float);  // 4.25 MB
    if (ws_size >= need) {
        float* y2 = (float*)d_ws;
        float* y3 = y2 + 1048576;
        pool_kernel<<<dim3(4352), dim3(256), 0, stream>>>(x2, x3, y2, y3);
        combine_kernel<<<dim3(1024), dim3(256), 0, stream>>>(x1, ff, y2, y3, out);
    } else {
        fused_ff_block3<<<dim3(512), dim3(256), 0, stream>>>(x1, x2, x3, ff, out);
    }
}

// Round 8
// 37.646 us; speedup vs baseline: 1.0312x; 1.0312x over previous
//
#include <hip/hip_runtime.h>
#include <math.h>

// Shapes (NCHW, f32):
//  x1: (8,128,128,128)  -> maxpool2 -> (8,128,64,64), tiled x2  in C
//  x2: (8, 32,256,256)  -> maxpool4 -> (8, 32,64,64), tiled x8  in C
//  x3: (8,  2,512,512)  -> maxpool8 -> (8,  2,64,64), tiled x128 in C
//  ff : (8,256,64,64)
//  out = relu(y1 + y2 + y3 + ff), (8,256,64,64)
//
// FINAL (= R0, the best measured variant: 36.5 us).
// Roofline accounting: compulsory traffic = 176 MB reads + 32 MB writes =
// 208 MB; 208 MB / 6.29 TB/s (m13 copy ceiling) = 33.1 us + ~3 us graph
// replay overhead = 36.2 us ~= measured 36.48 us. Across R0-R6 (occupancy
// 18->60%, NT loads/stores, fully-streaming 2-kernel layout) total
// bytes/time pinned at 5.4-5.7 TB/s delivery -> delivery-ceiling-bound.
// Single fused kernel, every input read exactly once:
//  - block = (b, h): one output row across all 256 channels.
//  - y3 (8x8 pool) and y2 (4x4 pool) staged in LDS.
//  - y1 (2x2 pool) computed in registers and reused for out channels c1 and
//    c1+128 (channel-tiling identity), so x1 is read once.

__global__ __launch_bounds__(256) void fused_ff_block3(
    const float* __restrict__ x1, const float* __restrict__ x2,
    const float* __restrict__ x3, const float* __restrict__ ff,
    float* __restrict__ out)
{
    __shared__ float y2s[32][64];   // 8 KiB
    __shared__ float y3s[2][64];    // 512 B

    const int bid = blockIdx.x;
    const int b   = bid >> 6;       // 0..7
    const int h   = bid & 63;       // output row 0..63
    const int tid = threadIdx.x;

    // ---- Phase 1: y3 row (2 ch x 64 w), each = max over 8x8 window of x3 ----
    if (tid < 128) {
        const int c3 = tid >> 6;    // 0..1
        const int w  = tid & 63;
        const float* p = x3 + (size_t)b * 524288 + (size_t)c3 * 262144
                            + (size_t)(h * 8) * 512 + (size_t)w * 8;
        float m = -INFINITY;
        #pragma unroll
        for (int r = 0; r < 8; ++r) {
            const float4 a = *reinterpret_cast<const float4*>(p + (size_t)r * 512);
            const float4 c = *reinterpret_cast<const float4*>(p + (size_t)r * 512 + 4);
            m = fmaxf(m, fmaxf(fmaxf(fmaxf(a.x, a.y), fmaxf(a.z, a.w)),
                               fmaxf(fmaxf(c.x, c.y), fmaxf(c.z, c.w))));
        }
        y3s[c3][w] = m;
    }

    // ---- Phase 2: y2 row (32 ch x 64 w), each = max over 4x4 window of x2 ----
    #pragma unroll
    for (int v = tid; v < 2048; v += 256) {
        const int c2 = v >> 6;      // 0..31
        const int w  = v & 63;
        const float* p = x2 + (size_t)b * 2097152 + (size_t)c2 * 65536
                            + (size_t)(h * 4) * 256 + (size_t)w * 4;
        float m = -INFINITY;
        #pragma unroll
        for (int r = 0; r < 4; ++r) {
            const float4 a = *reinterpret_cast<const float4*>(p + (size_t)r * 256);
            m = fmaxf(m, fmaxf(fmaxf(a.x, a.y), fmaxf(a.z, a.w)));
        }
        y2s[c2][w] = m;
    }

    __syncthreads();

    // ---- Phase 3: 2x2 pool of x1 in regs; combine + relu; write c1 and c1+128 ----
    const int w     = tid & 63;
    const int clane = tid >> 6;     // 0..3
    #pragma unroll 4
    for (int it = 0; it < 32; ++it) {
        const int c1 = it * 4 + clane;    // 0..127
        const float* p = x1 + (size_t)b * 2097152 + (size_t)c1 * 16384
                            + (size_t)(h * 2) * 128 + (size_t)w * 2;
        const float2 a  = *reinterpret_cast<const float2*>(p);
        const float2 bb = *reinterpret_cast<const float2*>(p + 128);
        const float p1 = fmaxf(fmaxf(a.x, a.y), fmaxf(bb.x, bb.y));
        const float s  = p1 + y2s[c1 & 31][w] + y3s[c1 & 1][w];

        const size_t obase = (size_t)b * 1048576 + (size_t)h * 64 + (size_t)w;
        const size_t o0 = obase + (size_t)c1 * 4096;
        const size_t o1 = obase + (size_t)(c1 + 128) * 4096;
        out[o0] = fmaxf(s + ff[o0], 0.0f);
        out[o1] = fmaxf(s + ff[o1], 0.0f);
    }
}

extern "C" void kernel_launch(void* const* d_in, const int* in_sizes, int n_in,
                              void* d_out, int out_size, void* d_ws, size_t ws_size,
                              hipStream_t stream) {
    const float* x1 = (const float*)d_in[0];
    const float* x2 = (const float*)d_in[1];
    const float* x3 = (const float*)d_in[2];
    const float* ff = (const float*)d_in[3];
    float* out = (float*)d_out;

    dim3 grid(512);   // 8 batches * 64 output rows
    dim3 block(256);
    fused_ff_block3<<<grid, block, 0, stream>>>(x1, x2, x3, ff, out);
}